// Round 2
// baseline (229.825 us; speedup 1.0000x reference)
//
#include <hip/hip_runtime.h>

#define N_NODES 50000
#define N_EDGES 800000
#define IN_CH 128
#define OUT_CH 64
#define HEADS 8
#define ROW 512           // OUT_CH*HEADS, floats per output row
#define NBLK_N 196        // ceil(N_NODES / 256)
#define NBLK_G 782        // ceil(N_NODES / 64)
#define NBLK_E4 782       // ceil(N_EDGES/4 / 256)  (200000 int4-groups)
#define NPARTIAL (NBLK_E4 * 4)
#define MAXDEG 64         // padded bucket; P(deg>=64) ~ 1e-13 for B(800k,1/50k)
#define XS_STRIDE 132     // floats per xs row: 128 + 4 pad (bank-spread, 16B-aligned)
#define WS_STRIDE 136     // shorts per wls col: 128 + 8 pad (272B, 16B-aligned)
#define CNT_STRIDE 16     // ints per counter: 1 counter per 64B cache line
                          // (800k atomics over 50k lines instead of 3125 lines;
                          //  kills same-line serialization at the coherence point)

typedef float f4 __attribute__((ext_vector_type(4)));
typedef short bf16x8 __attribute__((ext_vector_type(8)));

__device__ __forceinline__ float lrelu(float z) {
    return z > 0.0f ? z : 0.2f * z;
}

// fp32 -> bf16 (RNE) as raw 16-bit
__device__ __forceinline__ unsigned f2b(float f) {
    unsigned u = __float_as_uint(f);
    return (u + 0x7FFFu + ((u >> 16) & 1u)) >> 16;
}

// h = x @ W via MFMA bf16 (fp32 accumulate) -> hbuf (bf16 [N,64]);
// s[n] = h[n].attn[0:64], t[n] = h[n].attn[64:128] reduced from C-fragments.
// Also zeroes count[] (d_ws is re-poisoned to 0xAA before every call).
__global__ __launch_bounds__(256) void gemm_st(const float* __restrict__ x,
                                               const float* __restrict__ W,
                                               const float* __restrict__ attn,
                                               unsigned short* __restrict__ hbuf,
                                               float* __restrict__ s,
                                               float* __restrict__ t,
                                               int* __restrict__ count) {
    __shared__ float xs[64 * XS_STRIDE];            // 33.8 KB, fp32 x tile
    __shared__ unsigned short wls[64 * WS_STRIDE];  // 17.4 KB, W^T in bf16
    const int tid = threadIdx.x;
    if (blockIdx.x < NBLK_N) {
        int idx = blockIdx.x * 256 + tid;
        if (idx < N_NODES) count[idx * CNT_STRIDE] = 0;
    }
    const int base = blockIdx.x * 64;
    {   // stage W transposed -> bf16: wls[col][k]
        const float4* W4 = (const float4*)W;
#pragma unroll
        for (int j = 0; j < 8; ++j) {
            const int idx = tid + j * 256;   // float4 index into [128][16]
            const int k = idx >> 4;
            const int c = (idx & 15) * 4;
            const float4 v = W4[idx];
            wls[(c + 0) * WS_STRIDE + k] = (unsigned short)f2b(v.x);
            wls[(c + 1) * WS_STRIDE + k] = (unsigned short)f2b(v.y);
            wls[(c + 2) * WS_STRIDE + k] = (unsigned short)f2b(v.z);
            wls[(c + 3) * WS_STRIDE + k] = (unsigned short)f2b(v.w);
        }
    }
    {   // stage x tile fp32, coalesced float4, guarded
        const float4* x4 = (const float4*)x;
#pragma unroll
        for (int j = 0; j < 8; ++j) {
            const int idx = tid + j * 256;   // float4 index into [64][32]
            const int r = idx >> 5;
            const int kq = idx & 31;
            const int row = base + r;
            float4 v = make_float4(0.f, 0.f, 0.f, 0.f);
            if (row < N_NODES) v = x4[row * 32 + kq];
            *(float4*)&xs[r * XS_STRIDE + kq * 4] = v;
        }
    }
    __syncthreads();
    const int w = tid >> 6, lane = tid & 63;
    const int m = lane & 15;       // A row / B-C col within tile
    const int kq = lane >> 4;      // k-chunk quad / C row-quad
    // A-fragments (4 kb): read fp32, convert RNE to bf16
    bf16x8 afr[4];
#pragma unroll
    for (int kb = 0; kb < 4; ++kb) {
        const float* p = &xs[(w * 16 + m) * XS_STRIDE + kb * 32 + kq * 8];
        const float4 lo = *(const float4*)p;
        const float4 hi = *(const float4*)(p + 4);
        bf16x8 a;
        a[0] = (short)f2b(lo.x); a[1] = (short)f2b(lo.y);
        a[2] = (short)f2b(lo.z); a[3] = (short)f2b(lo.w);
        a[4] = (short)f2b(hi.x); a[5] = (short)f2b(hi.y);
        a[6] = (short)f2b(hi.z); a[7] = (short)f2b(hi.w);
        afr[kb] = a;
    }
    float sacc[4] = {0.f, 0.f, 0.f, 0.f};
    float tacc[4] = {0.f, 0.f, 0.f, 0.f};
#pragma unroll
    for (int ct = 0; ct < 4; ++ct) {          // 4 col-tiles of 16
        f4 acc = {0.f, 0.f, 0.f, 0.f};
#pragma unroll
        for (int kb = 0; kb < 4; ++kb) {
            const bf16x8 b = *(const bf16x8*)&wls[(ct * 16 + m) * WS_STRIDE + kb * 32 + kq * 8];
            acc = __builtin_amdgcn_mfma_f32_16x16x32_bf16(afr[kb], b, acc, 0, 0, 0);
        }
        const float a1 = attn[ct * 16 + m];
        const float a2 = attn[64 + ct * 16 + m];
#pragma unroll
        for (int r = 0; r < 4; ++r) {
            sacc[r] = fmaf(acc[r], a1, sacc[r]);
            tacc[r] = fmaf(acc[r], a2, tacc[r]);
            const int row = base + w * 16 + kq * 4 + r;   // C: row=(lane>>4)*4+reg
            if (row < N_NODES)
                hbuf[row * OUT_CH + ct * 16 + m] = (unsigned short)f2b(acc[r]);
        }
    }
    // reduce s/t over the 16 col-lanes (lane bits 0..3)
#pragma unroll
    for (int off = 1; off < 16; off <<= 1) {
#pragma unroll
        for (int r = 0; r < 4; ++r) {
            sacc[r] += __shfl_xor(sacc[r], off, 64);
            tacc[r] += __shfl_xor(tacc[r], off, 64);
        }
    }
    if (m == 0) {
#pragma unroll
        for (int r = 0; r < 4; ++r) {
            const int row = base + w * 16 + kq * 4 + r;
            if (row < N_NODES) { s[row] = sacc[r]; t[row] = tacc[r]; }
        }
    }
}

// Single edge pass, 4 edges/thread via int4 index loads. weight =
// exp(leaky_relu(s[dst]+t[src])), direct placement into padded bucket
// cv[dst*MAXDEG + rank] (rank = atomic return). Entry packed 4B:
// high16 = bf16 weight, low16 = src. Per-WAVE partial sums (no LDS, no
// barrier). NO device fences — ~150 us on non-coherent XCD L2s (R8).
// count[] is line-padded (CNT_STRIDE): one counter per 64B line so the
// 800k device-scope atomics don't serialize per-line at the coherence
// point (256 atomics/line -> 16 atomics/line).
__global__ __launch_bounds__(256) void edge_pass(const int4* __restrict__ ei4,
                                                 const int4* __restrict__ ej4,
                                                 const float* __restrict__ s,
                                                 const float* __restrict__ t,
                                                 int* __restrict__ count,
                                                 unsigned* __restrict__ cv,
                                                 float* __restrict__ partial) {
    const int g = blockIdx.x * 256 + threadIdx.x;   // int4-group id
    float p = 0.0f;
    if (g < N_EDGES / 4) {
        const int4 li = ei4[g];
        const int4 lj = ej4[g];
        const float v0 = __expf(lrelu(s[li.x] + t[lj.x]));
        const float v1 = __expf(lrelu(s[li.y] + t[lj.y]));
        const float v2 = __expf(lrelu(s[li.z] + t[lj.z]));
        const float v3 = __expf(lrelu(s[li.w] + t[lj.w]));
        const int r0 = atomicAdd(&count[li.x * CNT_STRIDE], 1);
        const int r1 = atomicAdd(&count[li.y * CNT_STRIDE], 1);
        const int r2 = atomicAdd(&count[li.z * CNT_STRIDE], 1);
        const int r3 = atomicAdd(&count[li.w * CNT_STRIDE], 1);
        if (r0 < MAXDEG) cv[li.x * MAXDEG + r0] = (f2b(v0) << 16) | (unsigned)lj.x;
        if (r1 < MAXDEG) cv[li.y * MAXDEG + r1] = (f2b(v1) << 16) | (unsigned)lj.y;
        if (r2 < MAXDEG) cv[li.z * MAXDEG + r2] = (f2b(v2) << 16) | (unsigned)lj.z;
        if (r3 < MAXDEG) cv[li.w * MAXDEG + r3] = (f2b(v3) << 16) | (unsigned)lj.w;
        p = (v0 + v1) + (v2 + v3);
    }
#pragma unroll
    for (int off = 32; off > 0; off >>= 1)
        p += __shfl_down(p, off, 64);
    if ((threadIdx.x & 63) == 0)
        partial[blockIdx.x * 4 + (threadIdx.x >> 6)] = p;
}

// single tiny block: invZ = 1 / sum(partial)
__global__ __launch_bounds__(256) void reduce_Z(const float* __restrict__ partial,
                                                float* __restrict__ invZ) {
    __shared__ float ls[4];
    float v = 0.0f;
    for (int i = threadIdx.x; i < NPARTIAL; i += 256) v += partial[i];
#pragma unroll
    for (int off = 32; off > 0; off >>= 1)
        v += __shfl_down(v, off, 64);
    const int lane = threadIdx.x & 63, w = threadIdx.x >> 6;
    if (lane == 0) ls[w] = v;
    __syncthreads();
    if (threadIdx.x == 0) *invZ = 1.0f / (ls[0] + ls[1] + ls[2] + ls[3]);
}

// one wave per destination node; slot = lane>>3 (8 edge slots), q = lane&7
// (16-byte chunk of the 128-byte bf16 h row). One uint4 load = 8 h values,
// 8 edges per wave-trip; cv for the next trip is prefetched so its latency
// hides under the h-load + FMA of the current trip. After the xor-reduce
// over slot bits every slot holds the full row sum, so slot doubles as the
// head index: 2 nontemporal float4 stores/lane cover all 8 head copies.
__global__ __launch_bounds__(256) void gather_out(const int* __restrict__ count,
                                                  const unsigned* __restrict__ cv,
                                                  const float* __restrict__ invZ,
                                                  const unsigned short* __restrict__ hbuf,
                                                  float* __restrict__ out) {
    const int n = blockIdx.x * 4 + (threadIdx.x >> 6);  // 12500*4 = 50000 exact
    const int lane = threadIdx.x & 63;
    const int slot = lane >> 3;          // edge slot 0..7
    const int q = lane & 7;              // 16B chunk 0..7 of the h row
    const float z = invZ[0];
    int cnt = count[n * CNT_STRIDE];
    cnt = cnt < MAXDEG ? cnt : MAXDEG;   // match edge_pass drop semantics
    const int base = n * MAXDEG;
    const uint4* h4 = (const uint4*)hbuf;
    f4 a0 = (f4)(0.0f);
    f4 a1 = (f4)(0.0f);
    unsigned pk = 0u;                    // src=0, weight=+0.0f for idle slots
    if (slot < cnt) pk = cv[base + slot];
    for (int i = 0; i < cnt; i += 8) {
        const int c = (int)(pk & 0xFFFFu);
        const float w = __uint_as_float(pk & 0xFFFF0000u);   // bf16 weight
        unsigned pk_n = 0u;
        const int ee = i + 8 + slot;
        if (ee < cnt) pk_n = cv[base + ee];                  // prefetch next trip
        const uint4 hv = h4[c * 8 + q];                      // 8 bf16 h values
        a0.x = fmaf(w, __uint_as_float(hv.x << 16),        a0.x);
        a0.y = fmaf(w, __uint_as_float(hv.x & 0xFFFF0000u), a0.y);
        a0.z = fmaf(w, __uint_as_float(hv.y << 16),        a0.z);
        a0.w = fmaf(w, __uint_as_float(hv.y & 0xFFFF0000u), a0.w);
        a1.x = fmaf(w, __uint_as_float(hv.z << 16),        a1.x);
        a1.y = fmaf(w, __uint_as_float(hv.z & 0xFFFF0000u), a1.y);
        a1.z = fmaf(w, __uint_as_float(hv.w << 16),        a1.z);
        a1.w = fmaf(w, __uint_as_float(hv.w & 0xFFFF0000u), a1.w);
        pk = pk_n;
    }
    // reduce across the 8 slots (lane bits 3,4,5); every slot ends with full sum
#pragma unroll
    for (int off = 8; off <= 32; off <<= 1) {
        a0.x += __shfl_xor(a0.x, off, 64);
        a0.y += __shfl_xor(a0.y, off, 64);
        a0.z += __shfl_xor(a0.z, off, 64);
        a0.w += __shfl_xor(a0.w, off, 64);
        a1.x += __shfl_xor(a1.x, off, 64);
        a1.y += __shfl_xor(a1.y, off, 64);
        a1.z += __shfl_xor(a1.z, off, 64);
        a1.w += __shfl_xor(a1.w, off, 64);
    }
    a0 *= z;
    a1 *= z;
    f4* out4 = (f4*)out;
    // head = slot: floats slot*64 + q*8 .. +7  ->  float4 idx slot*16 + q*2
    const int ob = n * 128 + slot * 16 + q * 2;
    __builtin_nontemporal_store(a0, out4 + ob);
    __builtin_nontemporal_store(a1, out4 + ob + 1);
}

extern "C" void kernel_launch(void* const* d_in, const int* in_sizes, int n_in,
                              void* d_out, int out_size, void* d_ws, size_t ws_size,
                              hipStream_t stream) {
    const float* x    = (const float*)d_in[0];
    const int*   eidx = (const int*)d_in[1];
    const float* W    = (const float*)d_in[2];
    const float* attn = (const float*)d_in[3];
    float* out = (float*)d_out;

    unsigned short* hbuf = (unsigned short*)d_ws;           // 3,200,000 bf16 (6.4 MB)
    unsigned* cv   = (unsigned*)(hbuf + N_NODES * OUT_CH);  // 50,000*64 u32 (12.8 MB)
    float* s       = (float*)(cv + N_NODES * MAXDEG);       // 50,000
    float* t       = s + N_NODES;                           // 50,000
    float* partial = t + N_NODES;                           // 3,128
    float* invZ    = partial + NPARTIAL;                    // 1
    int*   count   = (int*)(invZ + 1);                      // 50,000*16 line-padded (~23 MB total)

    const int4* ei4 = (const int4*)eidx;              // destinations
    const int4* ej4 = (const int4*)(eidx + N_EDGES);  // sources

    gemm_st   <<<NBLK_G, 256, 0, stream>>>(x, W, attn, hbuf, s, t, count);
    edge_pass <<<NBLK_E4, 256, 0, stream>>>(ei4, ej4, s, t, count, cv, partial);
    reduce_Z  <<<1, 256, 0, stream>>>(partial, invZ);
    gather_out<<<N_NODES / 4, 256, 0, stream>>>(count, cv, invZ, hbuf, out);
}

// Round 3
// 221.014 us; speedup vs baseline: 1.0399x; 1.0399x over previous
//
#include <hip/hip_runtime.h>

#define N_NODES 50000
#define N_EDGES 800000
#define IN_CH 128
#define OUT_CH 64
#define HEADS 8
#define ROW 512           // OUT_CH*HEADS, floats per output row
#define NBLK_N 196        // ceil(N_NODES / 256)
#define NBLK_G 782        // ceil(N_NODES / 64)
#define NBLK_E 3125       // N_EDGES / 256, 1 edge/thread (latency-bound: max waves)
#define NPARTIAL (NBLK_E * 4)
#define MAXDEG 64         // padded bucket; P(deg>=64) ~ 1e-13 for B(800k,1/50k)
#define XS_STRIDE 132     // floats per xs row: 128 + 4 pad (bank-spread, 16B-aligned)
#define WS_STRIDE 136     // shorts per wls col: 128 + 8 pad (272B, 16B-aligned)

typedef float f4 __attribute__((ext_vector_type(4)));
typedef short bf16x8 __attribute__((ext_vector_type(8)));

__device__ __forceinline__ float lrelu(float z) {
    return z > 0.0f ? z : 0.2f * z;
}

// fp32 -> bf16 (RNE) as raw 16-bit
__device__ __forceinline__ unsigned f2b(float f) {
    unsigned u = __float_as_uint(f);
    return (u + 0x7FFFu + ((u >> 16) & 1u)) >> 16;
}

// h = x @ W via MFMA bf16 (fp32 accumulate) -> hbuf (bf16 [N,64]);
// s[n] = h[n].attn[0:64], t[n] = h[n].attn[64:128] reduced from C-fragments.
// Also zeroes count[] (d_ws is re-poisoned to 0xAA before every call).
__global__ __launch_bounds__(256) void gemm_st(const float* __restrict__ x,
                                               const float* __restrict__ W,
                                               const float* __restrict__ attn,
                                               unsigned short* __restrict__ hbuf,
                                               float* __restrict__ s,
                                               float* __restrict__ t,
                                               int* __restrict__ count) {
    __shared__ float xs[64 * XS_STRIDE];            // 33.8 KB, fp32 x tile
    __shared__ unsigned short wls[64 * WS_STRIDE];  // 17.4 KB, W^T in bf16
    const int tid = threadIdx.x;
    if (blockIdx.x < NBLK_N) {
        int idx = blockIdx.x * 256 + tid;
        if (idx < N_NODES) count[idx] = 0;
    }
    const int base = blockIdx.x * 64;
    {   // stage W transposed -> bf16: wls[col][k]
        const float4* W4 = (const float4*)W;
#pragma unroll
        for (int j = 0; j < 8; ++j) {
            const int idx = tid + j * 256;   // float4 index into [128][16]
            const int k = idx >> 4;
            const int c = (idx & 15) * 4;
            const float4 v = W4[idx];
            wls[(c + 0) * WS_STRIDE + k] = (unsigned short)f2b(v.x);
            wls[(c + 1) * WS_STRIDE + k] = (unsigned short)f2b(v.y);
            wls[(c + 2) * WS_STRIDE + k] = (unsigned short)f2b(v.z);
            wls[(c + 3) * WS_STRIDE + k] = (unsigned short)f2b(v.w);
        }
    }
    {   // stage x tile fp32, coalesced float4, guarded
        const float4* x4 = (const float4*)x;
#pragma unroll
        for (int j = 0; j < 8; ++j) {
            const int idx = tid + j * 256;   // float4 index into [64][32]
            const int r = idx >> 5;
            const int kq = idx & 31;
            const int row = base + r;
            float4 v = make_float4(0.f, 0.f, 0.f, 0.f);
            if (row < N_NODES) v = x4[row * 32 + kq];
            *(float4*)&xs[r * XS_STRIDE + kq * 4] = v;
        }
    }
    __syncthreads();
    const int w = tid >> 6, lane = tid & 63;
    const int m = lane & 15;       // A row / B-C col within tile
    const int kq = lane >> 4;      // k-chunk quad / C row-quad
    // A-fragments (4 kb): read fp32, convert RNE to bf16
    bf16x8 afr[4];
#pragma unroll
    for (int kb = 0; kb < 4; ++kb) {
        const float* p = &xs[(w * 16 + m) * XS_STRIDE + kb * 32 + kq * 8];
        const float4 lo = *(const float4*)p;
        const float4 hi = *(const float4*)(p + 4);
        bf16x8 a;
        a[0] = (short)f2b(lo.x); a[1] = (short)f2b(lo.y);
        a[2] = (short)f2b(lo.z); a[3] = (short)f2b(lo.w);
        a[4] = (short)f2b(hi.x); a[5] = (short)f2b(hi.y);
        a[6] = (short)f2b(hi.z); a[7] = (short)f2b(hi.w);
        afr[kb] = a;
    }
    float sacc[4] = {0.f, 0.f, 0.f, 0.f};
    float tacc[4] = {0.f, 0.f, 0.f, 0.f};
#pragma unroll
    for (int ct = 0; ct < 4; ++ct) {          // 4 col-tiles of 16
        f4 acc = {0.f, 0.f, 0.f, 0.f};
#pragma unroll
        for (int kb = 0; kb < 4; ++kb) {
            const bf16x8 b = *(const bf16x8*)&wls[(ct * 16 + m) * WS_STRIDE + kb * 32 + kq * 8];
            acc = __builtin_amdgcn_mfma_f32_16x16x32_bf16(afr[kb], b, acc, 0, 0, 0);
        }
        const float a1 = attn[ct * 16 + m];
        const float a2 = attn[64 + ct * 16 + m];
#pragma unroll
        for (int r = 0; r < 4; ++r) {
            sacc[r] = fmaf(acc[r], a1, sacc[r]);
            tacc[r] = fmaf(acc[r], a2, tacc[r]);
            const int row = base + w * 16 + kq * 4 + r;   // C: row=(lane>>4)*4+reg
            if (row < N_NODES)
                hbuf[row * OUT_CH + ct * 16 + m] = (unsigned short)f2b(acc[r]);
        }
    }
    // reduce s/t over the 16 col-lanes (lane bits 0..3)
#pragma unroll
    for (int off = 1; off < 16; off <<= 1) {
#pragma unroll
        for (int r = 0; r < 4; ++r) {
            sacc[r] += __shfl_xor(sacc[r], off, 64);
            tacc[r] += __shfl_xor(tacc[r], off, 64);
        }
    }
    if (m == 0) {
#pragma unroll
        for (int r = 0; r < 4; ++r) {
            const int row = base + w * 16 + kq * 4 + r;
            if (row < N_NODES) { s[row] = sacc[r]; t[row] = tacc[r]; }
        }
    }
}

// Single edge pass, 1 edge/thread (latency-bound kernel: R2 profile showed
// 23% occupancy, 0.9% VALUBusy, 10% HBM at 4 edges/thread — the fix is
// wave-level parallelism, not fewer instructions). Grid 3125 blocks =
// 12500 waves (~49/CU demand -> occupancy saturates). weight =
// exp(leaky_relu(s[dst]+t[src])), direct placement into padded bucket
// cv[dst*MAXDEG + rank] (rank = atomic return). Entry packed 4B:
// high16 = bf16 weight, low16 = src. Per-WAVE partial sums (no LDS, no
// barrier). NO device fences — ~150 us on non-coherent XCD L2s (R8).
__global__ __launch_bounds__(256) void edge_pass(const int* __restrict__ ei,
                                                 const int* __restrict__ ej,
                                                 const float* __restrict__ s,
                                                 const float* __restrict__ t,
                                                 int* __restrict__ count,
                                                 unsigned* __restrict__ cv,
                                                 float* __restrict__ partial) {
    const int g = blockIdx.x * 256 + threadIdx.x;   // edge id, grid exact
    const int di = ei[g];
    const int sj = ej[g];
    const float v = __expf(lrelu(s[di] + t[sj]));
    const int r = atomicAdd(&count[di], 1);
    if (r < MAXDEG) cv[di * MAXDEG + r] = (f2b(v) << 16) | (unsigned)sj;
    float p = v;
#pragma unroll
    for (int off = 32; off > 0; off >>= 1)
        p += __shfl_down(p, off, 64);
    if ((threadIdx.x & 63) == 0)
        partial[blockIdx.x * 4 + (threadIdx.x >> 6)] = p;
}

// single tiny block: invZ = 1 / sum(partial)
__global__ __launch_bounds__(256) void reduce_Z(const float* __restrict__ partial,
                                                float* __restrict__ invZ) {
    __shared__ float ls[4];
    float v = 0.0f;
    for (int i = threadIdx.x; i < NPARTIAL; i += 256) v += partial[i];
#pragma unroll
    for (int off = 32; off > 0; off >>= 1)
        v += __shfl_down(v, off, 64);
    const int lane = threadIdx.x & 63, w = threadIdx.x >> 6;
    if (lane == 0) ls[w] = v;
    __syncthreads();
    if (threadIdx.x == 0) *invZ = 1.0f / (ls[0] + ls[1] + ls[2] + ls[3]);
}

// one wave per destination node; slot = lane>>3 (8 edge slots), q = lane&7
// (16-byte chunk of the 128-byte bf16 h row). One uint4 load = 8 h values,
// 8 edges per wave-trip; cv for the next trip is prefetched so its latency
// hides under the h-load + FMA of the current trip. After the xor-reduce
// over slot bits every slot holds the full row sum, so slot doubles as the
// head index: 2 nontemporal float4 stores/lane cover all 8 head copies.
__global__ __launch_bounds__(256) void gather_out(const int* __restrict__ count,
                                                  const unsigned* __restrict__ cv,
                                                  const float* __restrict__ invZ,
                                                  const unsigned short* __restrict__ hbuf,
                                                  float* __restrict__ out) {
    const int n = blockIdx.x * 4 + (threadIdx.x >> 6);  // 12500*4 = 50000 exact
    const int lane = threadIdx.x & 63;
    const int slot = lane >> 3;          // edge slot 0..7
    const int q = lane & 7;              // 16B chunk 0..7 of the h row
    const float z = invZ[0];
    int cnt = count[n];
    cnt = cnt < MAXDEG ? cnt : MAXDEG;   // match edge_pass drop semantics
    const int base = n * MAXDEG;
    const uint4* h4 = (const uint4*)hbuf;
    f4 a0 = (f4)(0.0f);
    f4 a1 = (f4)(0.0f);
    unsigned pk = 0u;                    // src=0, weight=+0.0f for idle slots
    if (slot < cnt) pk = cv[base + slot];
    for (int i = 0; i < cnt; i += 8) {
        const int c = (int)(pk & 0xFFFFu);
        const float w = __uint_as_float(pk & 0xFFFF0000u);   // bf16 weight
        unsigned pk_n = 0u;
        const int ee = i + 8 + slot;
        if (ee < cnt) pk_n = cv[base + ee];                  // prefetch next trip
        const uint4 hv = h4[c * 8 + q];                      // 8 bf16 h values
        a0.x = fmaf(w, __uint_as_float(hv.x << 16),        a0.x);
        a0.y = fmaf(w, __uint_as_float(hv.x & 0xFFFF0000u), a0.y);
        a0.z = fmaf(w, __uint_as_float(hv.y << 16),        a0.z);
        a0.w = fmaf(w, __uint_as_float(hv.y & 0xFFFF0000u), a0.w);
        a1.x = fmaf(w, __uint_as_float(hv.z << 16),        a1.x);
        a1.y = fmaf(w, __uint_as_float(hv.z & 0xFFFF0000u), a1.y);
        a1.z = fmaf(w, __uint_as_float(hv.w << 16),        a1.z);
        a1.w = fmaf(w, __uint_as_float(hv.w & 0xFFFF0000u), a1.w);
        pk = pk_n;
    }
    // reduce across the 8 slots (lane bits 3,4,5); every slot ends with full sum
#pragma unroll
    for (int off = 8; off <= 32; off <<= 1) {
        a0.x += __shfl_xor(a0.x, off, 64);
        a0.y += __shfl_xor(a0.y, off, 64);
        a0.z += __shfl_xor(a0.z, off, 64);
        a0.w += __shfl_xor(a0.w, off, 64);
        a1.x += __shfl_xor(a1.x, off, 64);
        a1.y += __shfl_xor(a1.y, off, 64);
        a1.z += __shfl_xor(a1.z, off, 64);
        a1.w += __shfl_xor(a1.w, off, 64);
    }
    a0 *= z;
    a1 *= z;
    f4* out4 = (f4*)out;
    // head = slot: floats slot*64 + q*8 .. +7  ->  float4 idx slot*16 + q*2
    const int ob = n * 128 + slot * 16 + q * 2;
    __builtin_nontemporal_store(a0, out4 + ob);
    __builtin_nontemporal_store(a1, out4 + ob + 1);
}

extern "C" void kernel_launch(void* const* d_in, const int* in_sizes, int n_in,
                              void* d_out, int out_size, void* d_ws, size_t ws_size,
                              hipStream_t stream) {
    const float* x    = (const float*)d_in[0];
    const int*   eidx = (const int*)d_in[1];
    const float* W    = (const float*)d_in[2];
    const float* attn = (const float*)d_in[3];
    float* out = (float*)d_out;

    unsigned short* hbuf = (unsigned short*)d_ws;           // 3,200,000 bf16 (6.4 MB)
    unsigned* cv   = (unsigned*)(hbuf + N_NODES * OUT_CH);  // 50,000*64 u32 (12.8 MB)
    float* s       = (float*)(cv + N_NODES * MAXDEG);       // 50,000
    float* t       = s + N_NODES;                           // 50,000
    float* partial = t + N_NODES;                           // 12,500
    float* invZ    = partial + NPARTIAL;                    // 1
    int*   count   = (int*)(invZ + 1);                      // 50,000  (~20 MB total)

    const int* ei = eidx;              // destinations
    const int* ej = eidx + N_EDGES;    // sources

    gemm_st   <<<NBLK_G, 256, 0, stream>>>(x, W, attn, hbuf, s, t, count);
    edge_pass <<<NBLK_E, 256, 0, stream>>>(ei, ej, s, t, count, cv, partial);
    reduce_Z  <<<1, 256, 0, stream>>>(partial, invZ);
    gather_out<<<N_NODES / 4, 256, 0, stream>>>(count, cv, invZ, hbuf, out);
}

// Round 4
// 216.086 us; speedup vs baseline: 1.0636x; 1.0228x over previous
//
#include <hip/hip_runtime.h>

#define N_NODES 50000
#define N_EDGES 800000
#define IN_CH 128
#define OUT_CH 64
#define HEADS 8
#define ROW 512           // OUT_CH*HEADS, floats per output row
#define NBLK_N 196        // ceil(N_NODES / 256)
#define NBLK_G 782        // ceil(N_NODES / 64)
#define NBLK_E4 782       // ceil(N_EDGES/4 / 256)  (200000 int4-groups)
#define NPARTIAL (NBLK_E4 * 4)
#define MAXDEG 64         // padded bucket; P(deg>=64) ~ 1e-13 for B(800k,1/50k)
#define XS_STRIDE 132     // floats per xs row: 128 + 4 pad (bank-spread, 16B-aligned)
#define WS_STRIDE 136     // shorts per wls col: 128 + 8 pad (272B, 16B-aligned)

typedef float f4 __attribute__((ext_vector_type(4)));
typedef short bf16x8 __attribute__((ext_vector_type(8)));

__device__ __forceinline__ float lrelu(float z) {
    return z > 0.0f ? z : 0.2f * z;
}

// fp32 -> bf16 (RNE) as raw 16-bit
__device__ __forceinline__ unsigned f2b(float f) {
    unsigned u = __float_as_uint(f);
    return (u + 0x7FFFu + ((u >> 16) & 1u)) >> 16;
}

// h = x @ W via MFMA bf16 (fp32 accumulate) -> hbuf (bf16 [N,64]);
// s[n] = h[n].attn[0:64], t[n] = h[n].attn[64:128] reduced from C-fragments.
// Also zeroes count[] (d_ws is re-poisoned to 0xAA before every call).
__global__ __launch_bounds__(256) void gemm_st(const float* __restrict__ x,
                                               const float* __restrict__ W,
                                               const float* __restrict__ attn,
                                               unsigned short* __restrict__ hbuf,
                                               float* __restrict__ s,
                                               float* __restrict__ t,
                                               int* __restrict__ count) {
    __shared__ float xs[64 * XS_STRIDE];            // 33.8 KB, fp32 x tile
    __shared__ unsigned short wls[64 * WS_STRIDE];  // 17.4 KB, W^T in bf16
    const int tid = threadIdx.x;
    if (blockIdx.x < NBLK_N) {
        int idx = blockIdx.x * 256 + tid;
        if (idx < N_NODES) count[idx] = 0;
    }
    const int base = blockIdx.x * 64;
    {   // stage W transposed -> bf16: wls[col][k]
        const float4* W4 = (const float4*)W;
#pragma unroll
        for (int j = 0; j < 8; ++j) {
            const int idx = tid + j * 256;   // float4 index into [128][16]
            const int k = idx >> 4;
            const int c = (idx & 15) * 4;
            const float4 v = W4[idx];
            wls[(c + 0) * WS_STRIDE + k] = (unsigned short)f2b(v.x);
            wls[(c + 1) * WS_STRIDE + k] = (unsigned short)f2b(v.y);
            wls[(c + 2) * WS_STRIDE + k] = (unsigned short)f2b(v.z);
            wls[(c + 3) * WS_STRIDE + k] = (unsigned short)f2b(v.w);
        }
    }
    {   // stage x tile fp32, coalesced float4, guarded
        const float4* x4 = (const float4*)x;
#pragma unroll
        for (int j = 0; j < 8; ++j) {
            const int idx = tid + j * 256;   // float4 index into [64][32]
            const int r = idx >> 5;
            const int kq = idx & 31;
            const int row = base + r;
            float4 v = make_float4(0.f, 0.f, 0.f, 0.f);
            if (row < N_NODES) v = x4[row * 32 + kq];
            *(float4*)&xs[r * XS_STRIDE + kq * 4] = v;
        }
    }
    __syncthreads();
    const int w = tid >> 6, lane = tid & 63;
    const int m = lane & 15;       // A row / B-C col within tile
    const int kq = lane >> 4;      // k-chunk quad / C row-quad
    // A-fragments (4 kb): read fp32, convert RNE to bf16
    bf16x8 afr[4];
#pragma unroll
    for (int kb = 0; kb < 4; ++kb) {
        const float* p = &xs[(w * 16 + m) * XS_STRIDE + kb * 32 + kq * 8];
        const float4 lo = *(const float4*)p;
        const float4 hi = *(const float4*)(p + 4);
        bf16x8 a;
        a[0] = (short)f2b(lo.x); a[1] = (short)f2b(lo.y);
        a[2] = (short)f2b(lo.z); a[3] = (short)f2b(lo.w);
        a[4] = (short)f2b(hi.x); a[5] = (short)f2b(hi.y);
        a[6] = (short)f2b(hi.z); a[7] = (short)f2b(hi.w);
        afr[kb] = a;
    }
    float sacc[4] = {0.f, 0.f, 0.f, 0.f};
    float tacc[4] = {0.f, 0.f, 0.f, 0.f};
#pragma unroll
    for (int ct = 0; ct < 4; ++ct) {          // 4 col-tiles of 16
        f4 acc = {0.f, 0.f, 0.f, 0.f};
#pragma unroll
        for (int kb = 0; kb < 4; ++kb) {
            const bf16x8 b = *(const bf16x8*)&wls[(ct * 16 + m) * WS_STRIDE + kb * 32 + kq * 8];
            acc = __builtin_amdgcn_mfma_f32_16x16x32_bf16(afr[kb], b, acc, 0, 0, 0);
        }
        const float a1 = attn[ct * 16 + m];
        const float a2 = attn[64 + ct * 16 + m];
#pragma unroll
        for (int r = 0; r < 4; ++r) {
            sacc[r] = fmaf(acc[r], a1, sacc[r]);
            tacc[r] = fmaf(acc[r], a2, tacc[r]);
            const int row = base + w * 16 + kq * 4 + r;   // C: row=(lane>>4)*4+reg
            if (row < N_NODES)
                hbuf[row * OUT_CH + ct * 16 + m] = (unsigned short)f2b(acc[r]);
        }
    }
    // reduce s/t over the 16 col-lanes (lane bits 0..3)
#pragma unroll
    for (int off = 1; off < 16; off <<= 1) {
#pragma unroll
        for (int r = 0; r < 4; ++r) {
            sacc[r] += __shfl_xor(sacc[r], off, 64);
            tacc[r] += __shfl_xor(tacc[r], off, 64);
        }
    }
    if (m == 0) {
#pragma unroll
        for (int r = 0; r < 4; ++r) {
            const int row = base + w * 16 + kq * 4 + r;
            if (row < N_NODES) { s[row] = sacc[r]; t[row] = tacc[r]; }
        }
    }
}

// Single edge pass, 4 edges/thread via int4 index loads (best-measured
// config, R1). ATOMICS ISSUE FIRST: the rank atomics depend only on the
// index load, so issuing them before the s/t gathers + exp lets their
// ~600cy round-trip overlap the gather+exp latency instead of serializing
// after it (R2 profile: 0.9% VALUBusy, 23% occupancy -> chain-latency
// bound). weight = exp(leaky_relu(s[dst]+t[src])), placed into padded
// bucket cv[dst*MAXDEG + rank]; entry packed 4B: high16 = bf16 weight,
// low16 = src. Per-WAVE partial sums (no LDS, no barrier). NO device
// fences — ~150 us on non-coherent XCD L2s (R8).
__global__ __launch_bounds__(256) void edge_pass(const int4* __restrict__ ei4,
                                                 const int4* __restrict__ ej4,
                                                 const float* __restrict__ s,
                                                 const float* __restrict__ t,
                                                 int* __restrict__ count,
                                                 unsigned* __restrict__ cv,
                                                 float* __restrict__ partial) {
    const int g = blockIdx.x * 256 + threadIdx.x;   // int4-group id
    float p = 0.0f;
    if (g < N_EDGES / 4) {
        const int4 li = ei4[g];
        const int4 lj = ej4[g];
        // rank atomics first — overlap their latency with the gathers below
        const int r0 = atomicAdd(&count[li.x], 1);
        const int r1 = atomicAdd(&count[li.y], 1);
        const int r2 = atomicAdd(&count[li.z], 1);
        const int r3 = atomicAdd(&count[li.w], 1);
        const float v0 = __expf(lrelu(s[li.x] + t[lj.x]));
        const float v1 = __expf(lrelu(s[li.y] + t[lj.y]));
        const float v2 = __expf(lrelu(s[li.z] + t[lj.z]));
        const float v3 = __expf(lrelu(s[li.w] + t[lj.w]));
        if (r0 < MAXDEG) cv[li.x * MAXDEG + r0] = (f2b(v0) << 16) | (unsigned)lj.x;
        if (r1 < MAXDEG) cv[li.y * MAXDEG + r1] = (f2b(v1) << 16) | (unsigned)lj.y;
        if (r2 < MAXDEG) cv[li.z * MAXDEG + r2] = (f2b(v2) << 16) | (unsigned)lj.z;
        if (r3 < MAXDEG) cv[li.w * MAXDEG + r3] = (f2b(v3) << 16) | (unsigned)lj.w;
        p = (v0 + v1) + (v2 + v3);
    }
#pragma unroll
    for (int off = 32; off > 0; off >>= 1)
        p += __shfl_down(p, off, 64);
    if ((threadIdx.x & 63) == 0)
        partial[blockIdx.x * 4 + (threadIdx.x >> 6)] = p;
}

// single tiny block: invZ = 1 / sum(partial)
__global__ __launch_bounds__(256) void reduce_Z(const float* __restrict__ partial,
                                                float* __restrict__ invZ) {
    __shared__ float ls[4];
    float v = 0.0f;
    for (int i = threadIdx.x; i < NPARTIAL; i += 256) v += partial[i];
#pragma unroll
    for (int off = 32; off > 0; off >>= 1)
        v += __shfl_down(v, off, 64);
    const int lane = threadIdx.x & 63, w = threadIdx.x >> 6;
    if (lane == 0) ls[w] = v;
    __syncthreads();
    if (threadIdx.x == 0) *invZ = 1.0f / (ls[0] + ls[1] + ls[2] + ls[3]);
}

// one wave per destination node; slot = lane>>3 (8 edge slots), q = lane&7
// (16-byte chunk of the 128-byte bf16 h row). One uint4 load = 8 h values,
// 8 edges per wave-trip; cv for the next trip is prefetched so its latency
// hides under the h-load + FMA of the current trip. After the xor-reduce
// over slot bits every slot holds the full row sum, so slot doubles as the
// head index: 2 nontemporal float4 stores/lane cover all 8 head copies.
__global__ __launch_bounds__(256) void gather_out(const int* __restrict__ count,
                                                  const unsigned* __restrict__ cv,
                                                  const float* __restrict__ invZ,
                                                  const unsigned short* __restrict__ hbuf,
                                                  float* __restrict__ out) {
    const int n = blockIdx.x * 4 + (threadIdx.x >> 6);  // 12500*4 = 50000 exact
    const int lane = threadIdx.x & 63;
    const int slot = lane >> 3;          // edge slot 0..7
    const int q = lane & 7;              // 16B chunk 0..7 of the h row
    const float z = invZ[0];
    int cnt = count[n];
    cnt = cnt < MAXDEG ? cnt : MAXDEG;   // match edge_pass drop semantics
    const int base = n * MAXDEG;
    const uint4* h4 = (const uint4*)hbuf;
    f4 a0 = (f4)(0.0f);
    f4 a1 = (f4)(0.0f);
    unsigned pk = 0u;                    // src=0, weight=+0.0f for idle slots
    if (slot < cnt) pk = cv[base + slot];
    for (int i = 0; i < cnt; i += 8) {
        const int c = (int)(pk & 0xFFFFu);
        const float w = __uint_as_float(pk & 0xFFFF0000u);   // bf16 weight
        unsigned pk_n = 0u;
        const int ee = i + 8 + slot;
        if (ee < cnt) pk_n = cv[base + ee];                  // prefetch next trip
        const uint4 hv = h4[c * 8 + q];                      // 8 bf16 h values
        a0.x = fmaf(w, __uint_as_float(hv.x << 16),        a0.x);
        a0.y = fmaf(w, __uint_as_float(hv.x & 0xFFFF0000u), a0.y);
        a0.z = fmaf(w, __uint_as_float(hv.y << 16),        a0.z);
        a0.w = fmaf(w, __uint_as_float(hv.y & 0xFFFF0000u), a0.w);
        a1.x = fmaf(w, __uint_as_float(hv.z << 16),        a1.x);
        a1.y = fmaf(w, __uint_as_float(hv.z & 0xFFFF0000u), a1.y);
        a1.z = fmaf(w, __uint_as_float(hv.w << 16),        a1.z);
        a1.w = fmaf(w, __uint_as_float(hv.w & 0xFFFF0000u), a1.w);
        pk = pk_n;
    }
    // reduce across the 8 slots (lane bits 3,4,5); every slot ends with full sum
#pragma unroll
    for (int off = 8; off <= 32; off <<= 1) {
        a0.x += __shfl_xor(a0.x, off, 64);
        a0.y += __shfl_xor(a0.y, off, 64);
        a0.z += __shfl_xor(a0.z, off, 64);
        a0.w += __shfl_xor(a0.w, off, 64);
        a1.x += __shfl_xor(a1.x, off, 64);
        a1.y += __shfl_xor(a1.y, off, 64);
        a1.z += __shfl_xor(a1.z, off, 64);
        a1.w += __shfl_xor(a1.w, off, 64);
    }
    a0 *= z;
    a1 *= z;
    f4* out4 = (f4*)out;
    // head = slot: floats slot*64 + q*8 .. +7  ->  float4 idx slot*16 + q*2
    const int ob = n * 128 + slot * 16 + q * 2;
    __builtin_nontemporal_store(a0, out4 + ob);
    __builtin_nontemporal_store(a1, out4 + ob + 1);
}

extern "C" void kernel_launch(void* const* d_in, const int* in_sizes, int n_in,
                              void* d_out, int out_size, void* d_ws, size_t ws_size,
                              hipStream_t stream) {
    const float* x    = (const float*)d_in[0];
    const int*   eidx = (const int*)d_in[1];
    const float* W    = (const float*)d_in[2];
    const float* attn = (const float*)d_in[3];
    float* out = (float*)d_out;

    unsigned short* hbuf = (unsigned short*)d_ws;           // 3,200,000 bf16 (6.4 MB)
    unsigned* cv   = (unsigned*)(hbuf + N_NODES * OUT_CH);  // 50,000*64 u32 (12.8 MB)
    float* s       = (float*)(cv + N_NODES * MAXDEG);       // 50,000
    float* t       = s + N_NODES;                           // 50,000
    float* partial = t + N_NODES;                           // 3,128
    float* invZ    = partial + NPARTIAL;                    // 1
    int*   count   = (int*)(invZ + 1);                      // 50,000  (~19.9 MB total)

    const int4* ei4 = (const int4*)eidx;              // destinations
    const int4* ej4 = (const int4*)(eidx + N_EDGES);  // sources

    gemm_st   <<<NBLK_G, 256, 0, stream>>>(x, W, attn, hbuf, s, t, count);
    edge_pass <<<NBLK_E4, 256, 0, stream>>>(ei4, ej4, s, t, count, cv, partial);
    reduce_Z  <<<1, 256, 0, stream>>>(partial, invZ);
    gather_out<<<N_NODES / 4, 256, 0, stream>>>(count, cv, invZ, hbuf, out);
}

// Round 5
// 192.340 us; speedup vs baseline: 1.1949x; 1.1235x over previous
//
#include <hip/hip_runtime.h>

#define N_NODES 50000
#define N_EDGES 800000
#define IN_CH 128
#define OUT_CH 64
#define HEADS 8
#define ROW 512           // OUT_CH*HEADS, floats per output row
#define NBLK_G 782        // ceil(N_NODES / 64)
#define NBLK_A 782        // ceil(N_EDGES/4 / 256)  (200000 int4-groups)
#define NBIN 196          // dst>>8 bins (dst<50000 -> bin 0..195), 256 dsts/bin
#define BINCAP 4608       // per-bin edge capacity; load is Poisson(4082), 6.5-sigma pad
#define NPARTIAL NBIN
#define MAXDEG 64         // padded bucket; P(deg>=64) ~ 1e-13 for B(800k,1/50k)
#define XS_STRIDE 132     // floats per xs row: 128 + 4 pad (bank-spread, 16B-aligned)
#define WS_STRIDE 136     // shorts per wls col: 128 + 8 pad (272B, 16B-aligned)

typedef float f4 __attribute__((ext_vector_type(4)));
typedef short bf16x8 __attribute__((ext_vector_type(8)));

__device__ __forceinline__ float lrelu(float z) {
    return z > 0.0f ? z : 0.2f * z;
}

// fp32 -> bf16 (RNE) as raw 16-bit
__device__ __forceinline__ unsigned f2b(float f) {
    unsigned u = __float_as_uint(f);
    return (u + 0x7FFFu + ((u >> 16) & 1u)) >> 16;
}

// h = x @ W via MFMA bf16 (fp32 accumulate) -> hbuf (bf16 [N,64]);
// s[n] = h[n].attn[0:64], t[n] = h[n].attn[64:128] reduced from C-fragments.
// Also zeroes bin_count[] (196 ints; d_ws is re-poisoned to 0xAA every call).
// count[] no longer needs zeroing: weight_pass writes every count[d] fresh.
__global__ __launch_bounds__(256) void gemm_st(const float* __restrict__ x,
                                               const float* __restrict__ W,
                                               const float* __restrict__ attn,
                                               unsigned short* __restrict__ hbuf,
                                               float* __restrict__ s,
                                               float* __restrict__ t,
                                               int* __restrict__ bin_count) {
    __shared__ float xs[64 * XS_STRIDE];            // 33.8 KB, fp32 x tile
    __shared__ unsigned short wls[64 * WS_STRIDE];  // 17.4 KB, W^T in bf16
    const int tid = threadIdx.x;
    if (blockIdx.x == 0 && tid < NBIN) bin_count[tid] = 0;
    const int base = blockIdx.x * 64;
    {   // stage W transposed -> bf16: wls[col][k]
        const float4* W4 = (const float4*)W;
#pragma unroll
        for (int j = 0; j < 8; ++j) {
            const int idx = tid + j * 256;   // float4 index into [128][16]
            const int k = idx >> 4;
            const int c = (idx & 15) * 4;
            const float4 v = W4[idx];
            wls[(c + 0) * WS_STRIDE + k] = (unsigned short)f2b(v.x);
            wls[(c + 1) * WS_STRIDE + k] = (unsigned short)f2b(v.y);
            wls[(c + 2) * WS_STRIDE + k] = (unsigned short)f2b(v.z);
            wls[(c + 3) * WS_STRIDE + k] = (unsigned short)f2b(v.w);
        }
    }
    {   // stage x tile fp32, coalesced float4, guarded
        const float4* x4 = (const float4*)x;
#pragma unroll
        for (int j = 0; j < 8; ++j) {
            const int idx = tid + j * 256;   // float4 index into [64][32]
            const int r = idx >> 5;
            const int kq = idx & 31;
            const int row = base + r;
            float4 v = make_float4(0.f, 0.f, 0.f, 0.f);
            if (row < N_NODES) v = x4[row * 32 + kq];
            *(float4*)&xs[r * XS_STRIDE + kq * 4] = v;
        }
    }
    __syncthreads();
    const int w = tid >> 6, lane = tid & 63;
    const int m = lane & 15;       // A row / B-C col within tile
    const int kq = lane >> 4;      // k-chunk quad / C row-quad
    // A-fragments (4 kb): read fp32, convert RNE to bf16
    bf16x8 afr[4];
#pragma unroll
    for (int kb = 0; kb < 4; ++kb) {
        const float* p = &xs[(w * 16 + m) * XS_STRIDE + kb * 32 + kq * 8];
        const float4 lo = *(const float4*)p;
        const float4 hi = *(const float4*)(p + 4);
        bf16x8 a;
        a[0] = (short)f2b(lo.x); a[1] = (short)f2b(lo.y);
        a[2] = (short)f2b(lo.z); a[3] = (short)f2b(lo.w);
        a[4] = (short)f2b(hi.x); a[5] = (short)f2b(hi.y);
        a[6] = (short)f2b(hi.z); a[7] = (short)f2b(hi.w);
        afr[kb] = a;
    }
    float sacc[4] = {0.f, 0.f, 0.f, 0.f};
    float tacc[4] = {0.f, 0.f, 0.f, 0.f};
#pragma unroll
    for (int ct = 0; ct < 4; ++ct) {          // 4 col-tiles of 16
        f4 acc = {0.f, 0.f, 0.f, 0.f};
#pragma unroll
        for (int kb = 0; kb < 4; ++kb) {
            const bf16x8 b = *(const bf16x8*)&wls[(ct * 16 + m) * WS_STRIDE + kb * 32 + kq * 8];
            acc = __builtin_amdgcn_mfma_f32_16x16x32_bf16(afr[kb], b, acc, 0, 0, 0);
        }
        const float a1 = attn[ct * 16 + m];
        const float a2 = attn[64 + ct * 16 + m];
#pragma unroll
        for (int r = 0; r < 4; ++r) {
            sacc[r] = fmaf(acc[r], a1, sacc[r]);
            tacc[r] = fmaf(acc[r], a2, tacc[r]);
            const int row = base + w * 16 + kq * 4 + r;   // C: row=(lane>>4)*4+reg
            if (row < N_NODES)
                hbuf[row * OUT_CH + ct * 16 + m] = (unsigned short)f2b(acc[r]);
        }
    }
    // reduce s/t over the 16 col-lanes (lane bits 0..3)
#pragma unroll
    for (int off = 1; off < 16; off <<= 1) {
#pragma unroll
        for (int r = 0; r < 4; ++r) {
            sacc[r] += __shfl_xor(sacc[r], off, 64);
            tacc[r] += __shfl_xor(tacc[r], off, 64);
        }
    }
    if (m == 0) {
#pragma unroll
        for (int r = 0; r < 4; ++r) {
            const int row = base + w * 16 + kq * 4 + r;
            if (row < N_NODES) { s[row] = sacc[r]; t[row] = tacc[r]; }
        }
    }
}

// Pass A: bin edges by dst>>8 via per-block LDS histogram. Global atomics:
// one per (block, touched-bin) ~= 196/block (153k total, 5x fewer than
// 800k per-edge). binned entry packs (dst&255)<<16 | src (both fit 16b).
// Per-block per-bin chunks are contiguous (base from global reserve +
// LDS cursor), so writes land in ~20B runs instead of isolated 4B.
__global__ __launch_bounds__(256) void bin_pass(const int4* __restrict__ ei4,
                                                const int4* __restrict__ ej4,
                                                int* __restrict__ bin_count,
                                                unsigned* __restrict__ binned) {
    __shared__ unsigned hist[NBIN], base_s[NBIN], cur[NBIN];
    const int tid = threadIdx.x;
    if (tid < NBIN) { hist[tid] = 0u; cur[tid] = 0u; }
    __syncthreads();
    const int g = blockIdx.x * 256 + tid;   // int4-group id
    const bool act = g < N_EDGES / 4;
    int4 li = make_int4(0, 0, 0, 0), lj = make_int4(0, 0, 0, 0);
    if (act) {
        li = ei4[g];
        lj = ej4[g];
        atomicAdd(&hist[li.x >> 8], 1u);
        atomicAdd(&hist[li.y >> 8], 1u);
        atomicAdd(&hist[li.z >> 8], 1u);
        atomicAdd(&hist[li.w >> 8], 1u);
    }
    __syncthreads();
    if (tid < NBIN) {
        const unsigned c = hist[tid];
        base_s[tid] = c ? (unsigned)atomicAdd(&bin_count[tid], (int)c) : 0u;
    }
    __syncthreads();
    if (act) {
        const unsigned p0 = base_s[li.x >> 8] + atomicAdd(&cur[li.x >> 8], 1u);
        if (p0 < BINCAP) binned[(li.x >> 8) * BINCAP + p0] =
            ((unsigned)(li.x & 255) << 16) | (unsigned)lj.x;
        const unsigned p1 = base_s[li.y >> 8] + atomicAdd(&cur[li.y >> 8], 1u);
        if (p1 < BINCAP) binned[(li.y >> 8) * BINCAP + p1] =
            ((unsigned)(li.y & 255) << 16) | (unsigned)lj.y;
        const unsigned p2 = base_s[li.z >> 8] + atomicAdd(&cur[li.z >> 8], 1u);
        if (p2 < BINCAP) binned[(li.z >> 8) * BINCAP + p2] =
            ((unsigned)(li.z & 255) << 16) | (unsigned)lj.z;
        const unsigned p3 = base_s[li.w >> 8] + atomicAdd(&cur[li.w >> 8], 1u);
        if (p3 < BINCAP) binned[(li.w >> 8) * BINCAP + p3] =
            ((unsigned)(li.w & 255) << 16) | (unsigned)lj.w;
    }
}

// Pass B: one block per bin; the block owns ALL edges whose dst is in
// [bin*256, bin*256+256), so ranks come from fast LDS atomics (ZERO global
// atomics), buckets are built in 64KB LDS, and cv + count are written
// fully COALESCED (the block's cv region cv[bin*16384 .. +16384) is
// contiguous). s[] for the dst range is LDS-staged; the only remaining
// scattered op is the t[src] gather (1 per edge; t is 200KB, L2-resident).
// Z partials: one per bin.
__global__ __launch_bounds__(1024) void weight_pass(const unsigned* __restrict__ binned,
                                                    const int* __restrict__ bin_count,
                                                    const float* __restrict__ s,
                                                    const float* __restrict__ t,
                                                    unsigned* __restrict__ cv,
                                                    int* __restrict__ count,
                                                    float* __restrict__ partial) {
    __shared__ unsigned bkt[256 * MAXDEG];   // 64 KB
    __shared__ unsigned cnt_l[256];
    __shared__ float s_l[256];
    __shared__ float red[16];
    const int tid = threadIdx.x;
    const int bin = blockIdx.x;
    if (tid < 256) {
        cnt_l[tid] = 0u;
        const int d = bin * 256 + tid;
        s_l[tid] = (d < N_NODES) ? s[d] : 0.0f;
    }
    __syncthreads();
    int n = bin_count[bin];
    if (n > BINCAP) n = BINCAP;
    float zs = 0.0f;
    for (int i = tid; i < n; i += 1024) {
        const unsigned e = binned[bin * BINCAP + i];
        const int dl = (int)((e >> 16) & 255u);
        const int src = (int)(e & 0xFFFFu);
        const float w = __expf(lrelu(s_l[dl] + t[src]));
        zs += w;
        const unsigned r = atomicAdd(&cnt_l[dl], 1u);
        if (r < MAXDEG) bkt[dl * MAXDEG + r] = (f2b(w) << 16) | (unsigned)src;
    }
    __syncthreads();
    {   // coalesced cv flush: 16384 u32 = 4096 uint4 (slots >= cnt are garbage,
        // never read by gather_out)
        uint4* cv4 = (uint4*)(cv + bin * (256 * MAXDEG));
        const uint4* b4 = (const uint4*)bkt;
        for (int i = tid; i < 4096; i += 1024) cv4[i] = b4[i];
    }
    if (tid < 256) {
        const int d = bin * 256 + tid;
        if (d < N_NODES) count[d] = (int)cnt_l[tid];
    }
    // block Z partial
#pragma unroll
    for (int off = 32; off > 0; off >>= 1)
        zs += __shfl_down(zs, off, 64);
    if ((tid & 63) == 0) red[tid >> 6] = zs;
    __syncthreads();
    if (tid == 0) {
        float v = 0.0f;
#pragma unroll
        for (int k = 0; k < 16; ++k) v += red[k];
        partial[bin] = v;
    }
}

// single tiny block: invZ = 1 / sum(partial)
__global__ __launch_bounds__(256) void reduce_Z(const float* __restrict__ partial,
                                                float* __restrict__ invZ) {
    __shared__ float ls[4];
    float v = 0.0f;
    for (int i = threadIdx.x; i < NPARTIAL; i += 256) v += partial[i];
#pragma unroll
    for (int off = 32; off > 0; off >>= 1)
        v += __shfl_down(v, off, 64);
    const int lane = threadIdx.x & 63, w = threadIdx.x >> 6;
    if (lane == 0) ls[w] = v;
    __syncthreads();
    if (threadIdx.x == 0) *invZ = 1.0f / (ls[0] + ls[1] + ls[2] + ls[3]);
}

// one wave per destination node; slot = lane>>3 (8 edge slots), q = lane&7
// (16-byte chunk of the 128-byte bf16 h row). One uint4 load = 8 h values,
// 8 edges per wave-trip; cv for the next trip is prefetched so its latency
// hides under the h-load + FMA of the current trip. After the xor-reduce
// over slot bits every slot holds the full row sum, so slot doubles as the
// head index: 2 nontemporal float4 stores/lane cover all 8 head copies.
__global__ __launch_bounds__(256) void gather_out(const int* __restrict__ count,
                                                  const unsigned* __restrict__ cv,
                                                  const float* __restrict__ invZ,
                                                  const unsigned short* __restrict__ hbuf,
                                                  float* __restrict__ out) {
    const int n = blockIdx.x * 4 + (threadIdx.x >> 6);  // 12500*4 = 50000 exact
    const int lane = threadIdx.x & 63;
    const int slot = lane >> 3;          // edge slot 0..7
    const int q = lane & 7;              // 16B chunk 0..7 of the h row
    const float z = invZ[0];
    int cnt = count[n];
    cnt = cnt < MAXDEG ? cnt : MAXDEG;   // match weight_pass drop semantics
    const int base = n * MAXDEG;
    const uint4* h4 = (const uint4*)hbuf;
    f4 a0 = (f4)(0.0f);
    f4 a1 = (f4)(0.0f);
    unsigned pk = 0u;                    // src=0, weight=+0.0f for idle slots
    if (slot < cnt) pk = cv[base + slot];
    for (int i = 0; i < cnt; i += 8) {
        const int c = (int)(pk & 0xFFFFu);
        const float w = __uint_as_float(pk & 0xFFFF0000u);   // bf16 weight
        unsigned pk_n = 0u;
        const int ee = i + 8 + slot;
        if (ee < cnt) pk_n = cv[base + ee];                  // prefetch next trip
        const uint4 hv = h4[c * 8 + q];                      // 8 bf16 h values
        a0.x = fmaf(w, __uint_as_float(hv.x << 16),        a0.x);
        a0.y = fmaf(w, __uint_as_float(hv.x & 0xFFFF0000u), a0.y);
        a0.z = fmaf(w, __uint_as_float(hv.y << 16),        a0.z);
        a0.w = fmaf(w, __uint_as_float(hv.y & 0xFFFF0000u), a0.w);
        a1.x = fmaf(w, __uint_as_float(hv.z << 16),        a1.x);
        a1.y = fmaf(w, __uint_as_float(hv.z & 0xFFFF0000u), a1.y);
        a1.z = fmaf(w, __uint_as_float(hv.w << 16),        a1.z);
        a1.w = fmaf(w, __uint_as_float(hv.w & 0xFFFF0000u), a1.w);
        pk = pk_n;
    }
    // reduce across the 8 slots (lane bits 3,4,5); every slot ends with full sum
#pragma unroll
    for (int off = 8; off <= 32; off <<= 1) {
        a0.x += __shfl_xor(a0.x, off, 64);
        a0.y += __shfl_xor(a0.y, off, 64);
        a0.z += __shfl_xor(a0.z, off, 64);
        a0.w += __shfl_xor(a0.w, off, 64);
        a1.x += __shfl_xor(a1.x, off, 64);
        a1.y += __shfl_xor(a1.y, off, 64);
        a1.z += __shfl_xor(a1.z, off, 64);
        a1.w += __shfl_xor(a1.w, off, 64);
    }
    a0 *= z;
    a1 *= z;
    f4* out4 = (f4*)out;
    // head = slot: floats slot*64 + q*8 .. +7  ->  float4 idx slot*16 + q*2
    const int ob = n * 128 + slot * 16 + q * 2;
    __builtin_nontemporal_store(a0, out4 + ob);
    __builtin_nontemporal_store(a1, out4 + ob + 1);
}

extern "C" void kernel_launch(void* const* d_in, const int* in_sizes, int n_in,
                              void* d_out, int out_size, void* d_ws, size_t ws_size,
                              hipStream_t stream) {
    const float* x    = (const float*)d_in[0];
    const int*   eidx = (const int*)d_in[1];
    const float* W    = (const float*)d_in[2];
    const float* attn = (const float*)d_in[3];
    float* out = (float*)d_out;

    unsigned short* hbuf = (unsigned short*)d_ws;           // 3,200,000 bf16 (6.4 MB)
    unsigned* cv    = (unsigned*)(hbuf + N_NODES * OUT_CH); // 196*16384 u32 (12.85 MB)
    float* s        = (float*)(cv + NBIN * 256 * MAXDEG);   // 50,000
    float* t        = s + N_NODES;                          // 50,000
    float* partial  = t + N_NODES;                          // 196
    float* invZ     = partial + NPARTIAL;                   // 1
    int*   bin_count= (int*)(invZ + 1);                     // 196
    unsigned* binned= (unsigned*)(bin_count + NBIN);        // 196*4608 u32 (3.6 MB)

    const int4* ei4 = (const int4*)eidx;              // destinations
    const int4* ej4 = (const int4*)(eidx + N_EDGES);  // sources
    int* count = (int*)(binned + NBIN * BINCAP);      // 50,000 (written coalesced, no zeroing)

    gemm_st    <<<NBLK_G, 256, 0, stream>>>(x, W, attn, hbuf, s, t, bin_count);
    bin_pass   <<<NBLK_A, 256, 0, stream>>>(ei4, ej4, bin_count, binned);
    weight_pass<<<NBIN, 1024, 0, stream>>>(binned, bin_count, s, t, cv, count, partial);
    reduce_Z   <<<1, 256, 0, stream>>>(partial, invZ);
    gather_out <<<N_NODES / 4, 256, 0, stream>>>(count, cv, invZ, hbuf, out);
}

// Round 6
// 173.758 us; speedup vs baseline: 1.3227x; 1.1069x over previous
//
#include <hip/hip_runtime.h>

#define N_NODES 50000
#define N_EDGES 800000
#define IN_CH 128
#define OUT_CH 64
#define HEADS 8
#define ROW 512           // OUT_CH*HEADS, floats per output row
#define NBLK_G 782        // ceil(N_NODES / 64) gemm tiles
#define NBLK_A 782        // ceil(N_EDGES/4 / 256) bin blocks (200000 int4-groups)
#define NBIN 196          // dst>>8 bins (dst<50000 -> bin 0..195), 256 dsts/bin
#define BINCAP 4608       // per-bin edge capacity; load is Binom(800k,256/50k)=4082 mean, 6.5-sigma pad
#define MAXDEG 64         // padded bucket; P(deg>=64) ~ 1e-13 for B(800k,1/50k)
#define WS_STRIDE 136     // shorts per LDS row: 128 + 8 pad (272B, 16B-aligned)

typedef float f4 __attribute__((ext_vector_type(4)));
typedef short bf16x8 __attribute__((ext_vector_type(8)));

__device__ __forceinline__ float lrelu(float z) {
    return z > 0.0f ? z : 0.2f * z;
}

// fp32 -> bf16 (RNE) as raw 16-bit
__device__ __forceinline__ unsigned f2b(float f) {
    unsigned u = __float_as_uint(f);
    return (u + 0x7FFFu + ((u >> 16) & 1u)) >> 16;
}

// Fused kernel, parity-interleaved roles (R5: gemm and binning are
// independent; even blocks do a gemm tile, odd blocks a bin block, so
// every CU co-hosts compute-heavy and latency-bound waves and the bin
// stalls hide under MFMA/VALU).
//
// gemm role: h = x @ W via MFMA bf16 -> hbuf (bf16 [N,64]); s/t = h.attn
// halves. x is staged in LDS as bf16 (identical RNE conversion as before,
// done at staging) -> 34.8 KB total LDS -> 4 blocks/CU.
//
// bin role: bin edges by dst>>8 via per-block LDS histogram; one global
// atomic per touched (block,bin) (~196/block, 153k total vs 800k
// per-edge). binned entry packs (dst&255)<<16 | src. Per-block per-bin
// chunks contiguous -> ~20B write runs instead of isolated 4B.
__global__ __launch_bounds__(256) void gemm_bin(const float* __restrict__ x,
                                                const float* __restrict__ W,
                                                const float* __restrict__ attn,
                                                const int4* __restrict__ ei4,
                                                const int4* __restrict__ ej4,
                                                unsigned short* __restrict__ hbuf,
                                                float* __restrict__ s,
                                                float* __restrict__ t,
                                                int* __restrict__ bin_count,
                                                unsigned* __restrict__ binned) {
    __shared__ unsigned short xs[64 * WS_STRIDE];   // 17.4 KB, x tile in bf16
    __shared__ unsigned short wls[64 * WS_STRIDE];  // 17.4 KB, W^T in bf16
    const int tid = threadIdx.x;
    const int bid = blockIdx.x;

    if (bid & 1) {
        // ---------------- bin role (odd blocks) ----------------
        unsigned* hist = (unsigned*)xs;      // overlay: 3*196*4B = 2.4 KB
        unsigned* bse  = hist + NBIN;
        unsigned* cur  = bse + NBIN;
        if (tid < NBIN) { hist[tid] = 0u; cur[tid] = 0u; }
        __syncthreads();
        const int g = (bid >> 1) * 256 + tid;   // int4-group id
        const bool act = g < N_EDGES / 4;
        int4 li = make_int4(0, 0, 0, 0), lj = make_int4(0, 0, 0, 0);
        if (act) {
            li = ei4[g];
            lj = ej4[g];
            atomicAdd(&hist[li.x >> 8], 1u);
            atomicAdd(&hist[li.y >> 8], 1u);
            atomicAdd(&hist[li.z >> 8], 1u);
            atomicAdd(&hist[li.w >> 8], 1u);
        }
        __syncthreads();
        if (tid < NBIN) {
            const unsigned c = hist[tid];
            bse[tid] = c ? (unsigned)atomicAdd(&bin_count[tid], (int)c) : 0u;
        }
        __syncthreads();
        if (act) {
            const unsigned p0 = bse[li.x >> 8] + atomicAdd(&cur[li.x >> 8], 1u);
            if (p0 < BINCAP) binned[(li.x >> 8) * BINCAP + p0] =
                ((unsigned)(li.x & 255) << 16) | (unsigned)lj.x;
            const unsigned p1 = bse[li.y >> 8] + atomicAdd(&cur[li.y >> 8], 1u);
            if (p1 < BINCAP) binned[(li.y >> 8) * BINCAP + p1] =
                ((unsigned)(li.y & 255) << 16) | (unsigned)lj.y;
            const unsigned p2 = bse[li.z >> 8] + atomicAdd(&cur[li.z >> 8], 1u);
            if (p2 < BINCAP) binned[(li.z >> 8) * BINCAP + p2] =
                ((unsigned)(li.z & 255) << 16) | (unsigned)lj.z;
            const unsigned p3 = bse[li.w >> 8] + atomicAdd(&cur[li.w >> 8], 1u);
            if (p3 < BINCAP) binned[(li.w >> 8) * BINCAP + p3] =
                ((unsigned)(li.w & 255) << 16) | (unsigned)lj.w;
        }
        return;
    }

    // ---------------- gemm role (even blocks) ----------------
    const int base = (bid >> 1) * 64;
    {   // stage W transposed -> bf16: wls[col][k]
        const float4* W4 = (const float4*)W;
#pragma unroll
        for (int j = 0; j < 8; ++j) {
            const int idx = tid + j * 256;   // float4 index into [128][16]
            const int k = idx >> 4;
            const int c = (idx & 15) * 4;
            const float4 v = W4[idx];
            wls[(c + 0) * WS_STRIDE + k] = (unsigned short)f2b(v.x);
            wls[(c + 1) * WS_STRIDE + k] = (unsigned short)f2b(v.y);
            wls[(c + 2) * WS_STRIDE + k] = (unsigned short)f2b(v.z);
            wls[(c + 3) * WS_STRIDE + k] = (unsigned short)f2b(v.w);
        }
    }
    {   // stage x tile as bf16 (RNE at staging — same values as before)
        const float4* x4 = (const float4*)x;
#pragma unroll
        for (int j = 0; j < 8; ++j) {
            const int idx = tid + j * 256;   // float4 index into [64][32]
            const int r = idx >> 5;
            const int kq = idx & 31;
            const int row = base + r;
            float4 v = make_float4(0.f, 0.f, 0.f, 0.f);
            if (row < N_NODES) v = x4[row * 32 + kq];
            ushort4 pb;
            pb.x = (unsigned short)f2b(v.x);
            pb.y = (unsigned short)f2b(v.y);
            pb.z = (unsigned short)f2b(v.z);
            pb.w = (unsigned short)f2b(v.w);
            *(ushort4*)&xs[r * WS_STRIDE + kq * 4] = pb;
        }
    }
    __syncthreads();
    const int w = tid >> 6, lane = tid & 63;
    const int m = lane & 15;       // A row / B-C col within tile
    const int kq = lane >> 4;      // k-chunk quad / C row-quad
    bf16x8 afr[4];
#pragma unroll
    for (int kb = 0; kb < 4; ++kb)
        afr[kb] = *(const bf16x8*)&xs[(w * 16 + m) * WS_STRIDE + kb * 32 + kq * 8];
    float sacc[4] = {0.f, 0.f, 0.f, 0.f};
    float tacc[4] = {0.f, 0.f, 0.f, 0.f};
#pragma unroll
    for (int ct = 0; ct < 4; ++ct) {          // 4 col-tiles of 16
        f4 acc = {0.f, 0.f, 0.f, 0.f};
#pragma unroll
        for (int kb = 0; kb < 4; ++kb) {
            const bf16x8 b = *(const bf16x8*)&wls[(ct * 16 + m) * WS_STRIDE + kb * 32 + kq * 8];
            acc = __builtin_amdgcn_mfma_f32_16x16x32_bf16(afr[kb], b, acc, 0, 0, 0);
        }
        const float a1 = attn[ct * 16 + m];
        const float a2 = attn[64 + ct * 16 + m];
#pragma unroll
        for (int r = 0; r < 4; ++r) {
            sacc[r] = fmaf(acc[r], a1, sacc[r]);
            tacc[r] = fmaf(acc[r], a2, tacc[r]);
            const int row = base + w * 16 + kq * 4 + r;   // C: row=(lane>>4)*4+reg
            if (row < N_NODES)
                hbuf[row * OUT_CH + ct * 16 + m] = (unsigned short)f2b(acc[r]);
        }
    }
    // reduce s/t over the 16 col-lanes (lane bits 0..3)
#pragma unroll
    for (int off = 1; off < 16; off <<= 1) {
#pragma unroll
        for (int r = 0; r < 4; ++r) {
            sacc[r] += __shfl_xor(sacc[r], off, 64);
            tacc[r] += __shfl_xor(tacc[r], off, 64);
        }
    }
    if (m == 0) {
#pragma unroll
        for (int r = 0; r < 4; ++r) {
            const int row = base + w * 16 + kq * 4 + r;
            if (row < N_NODES) { s[row] = sacc[r]; t[row] = tacc[r]; }
        }
    }
}

// One block per bin; the block owns ALL edges whose dst is in
// [bin*256, bin*256+256): ranks from LDS atomics (zero global atomics),
// buckets built in 64KB LDS, cv + count written fully COALESCED. s[] for
// the dst range LDS-staged; only scattered op is the t[src] gather (L2-
// resident). Z contribution: ONE device-scope atomicAdd per block (R5:
// replaces the reduce_Z launch; kernel-boundary coherence covers the read).
__global__ __launch_bounds__(1024) void weight_pass(const unsigned* __restrict__ binned,
                                                    const int* __restrict__ bin_count,
                                                    const float* __restrict__ s,
                                                    const float* __restrict__ t,
                                                    unsigned* __restrict__ cv,
                                                    int* __restrict__ count,
                                                    float* __restrict__ Zsum) {
    __shared__ unsigned bkt[256 * MAXDEG];   // 64 KB
    __shared__ unsigned cnt_l[256];
    __shared__ float s_l[256];
    __shared__ float red[16];
    const int tid = threadIdx.x;
    const int bin = blockIdx.x;
    if (tid < 256) {
        cnt_l[tid] = 0u;
        const int d = bin * 256 + tid;
        s_l[tid] = (d < N_NODES) ? s[d] : 0.0f;
    }
    __syncthreads();
    int n = bin_count[bin];
    if (n > BINCAP) n = BINCAP;
    float zs = 0.0f;
    for (int i = tid; i < n; i += 1024) {
        const unsigned e = binned[bin * BINCAP + i];
        const int dl = (int)((e >> 16) & 255u);
        const int src = (int)(e & 0xFFFFu);
        const float w = __expf(lrelu(s_l[dl] + t[src]));
        zs += w;
        const unsigned r = atomicAdd(&cnt_l[dl], 1u);
        if (r < MAXDEG) bkt[dl * MAXDEG + r] = (f2b(w) << 16) | (unsigned)src;
    }
    __syncthreads();
    {   // coalesced cv flush: 16384 u32 = 4096 uint4 (slots >= cnt are garbage,
        // never read by gather_out)
        uint4* cv4 = (uint4*)(cv + bin * (256 * MAXDEG));
        const uint4* b4 = (const uint4*)bkt;
        for (int i = tid; i < 4096; i += 1024) cv4[i] = b4[i];
    }
    if (tid < 256) {
        const int d = bin * 256 + tid;
        if (d < N_NODES) count[d] = (int)cnt_l[tid];
    }
    // block Z partial -> one global atomic
#pragma unroll
    for (int off = 32; off > 0; off >>= 1)
        zs += __shfl_down(zs, off, 64);
    if ((tid & 63) == 0) red[tid >> 6] = zs;
    __syncthreads();
    if (tid == 0) {
        float v = 0.0f;
#pragma unroll
        for (int k = 0; k < 16; ++k) v += red[k];
        atomicAdd(Zsum, v);
    }
}

// one wave per destination node; slot = lane>>3 (8 edge slots), q = lane&7
// (16-byte chunk of the 128-byte bf16 h row). One uint4 load = 8 h values,
// 8 edges per wave-trip; cv for the next trip is prefetched so its latency
// hides under the h-load + FMA of the current trip. After the xor-reduce
// over slot bits every slot holds the full row sum, so slot doubles as the
// head index: 2 nontemporal float4 stores/lane cover all 8 head copies.
__global__ __launch_bounds__(256) void gather_out(const int* __restrict__ count,
                                                  const unsigned* __restrict__ cv,
                                                  const float* __restrict__ Zsum,
                                                  const unsigned short* __restrict__ hbuf,
                                                  float* __restrict__ out) {
    const int n = blockIdx.x * 4 + (threadIdx.x >> 6);  // 12500*4 = 50000 exact
    const int lane = threadIdx.x & 63;
    const int slot = lane >> 3;          // edge slot 0..7
    const int q = lane & 7;              // 16B chunk 0..7 of the h row
    const float z = 1.0f / Zsum[0];
    int cnt = count[n];
    cnt = cnt < MAXDEG ? cnt : MAXDEG;   // match weight_pass drop semantics
    const int base = n * MAXDEG;
    const uint4* h4 = (const uint4*)hbuf;
    f4 a0 = (f4)(0.0f);
    f4 a1 = (f4)(0.0f);
    unsigned pk = 0u;                    // src=0, weight=+0.0f for idle slots
    if (slot < cnt) pk = cv[base + slot];
    for (int i = 0; i < cnt; i += 8) {
        const int c = (int)(pk & 0xFFFFu);
        const float w = __uint_as_float(pk & 0xFFFF0000u);   // bf16 weight
        unsigned pk_n = 0u;
        const int ee = i + 8 + slot;
        if (ee < cnt) pk_n = cv[base + ee];                  // prefetch next trip
        const uint4 hv = h4[c * 8 + q];                      // 8 bf16 h values
        a0.x = fmaf(w, __uint_as_float(hv.x << 16),        a0.x);
        a0.y = fmaf(w, __uint_as_float(hv.x & 0xFFFF0000u), a0.y);
        a0.z = fmaf(w, __uint_as_float(hv.y << 16),        a0.z);
        a0.w = fmaf(w, __uint_as_float(hv.y & 0xFFFF0000u), a0.w);
        a1.x = fmaf(w, __uint_as_float(hv.z << 16),        a1.x);
        a1.y = fmaf(w, __uint_as_float(hv.z & 0xFFFF0000u), a1.y);
        a1.z = fmaf(w, __uint_as_float(hv.w << 16),        a1.z);
        a1.w = fmaf(w, __uint_as_float(hv.w & 0xFFFF0000u), a1.w);
        pk = pk_n;
    }
    // reduce across the 8 slots (lane bits 3,4,5); every slot ends with full sum
#pragma unroll
    for (int off = 8; off <= 32; off <<= 1) {
        a0.x += __shfl_xor(a0.x, off, 64);
        a0.y += __shfl_xor(a0.y, off, 64);
        a0.z += __shfl_xor(a0.z, off, 64);
        a0.w += __shfl_xor(a0.w, off, 64);
        a1.x += __shfl_xor(a1.x, off, 64);
        a1.y += __shfl_xor(a1.y, off, 64);
        a1.z += __shfl_xor(a1.z, off, 64);
        a1.w += __shfl_xor(a1.w, off, 64);
    }
    a0 *= z;
    a1 *= z;
    f4* out4 = (f4*)out;
    // head = slot: floats slot*64 + q*8 .. +7  ->  float4 idx slot*16 + q*2
    const int ob = n * 128 + slot * 16 + q * 2;
    __builtin_nontemporal_store(a0, out4 + ob);
    __builtin_nontemporal_store(a1, out4 + ob + 1);
}

extern "C" void kernel_launch(void* const* d_in, const int* in_sizes, int n_in,
                              void* d_out, int out_size, void* d_ws, size_t ws_size,
                              hipStream_t stream) {
    const float* x    = (const float*)d_in[0];
    const int*   eidx = (const int*)d_in[1];
    const float* W    = (const float*)d_in[2];
    const float* attn = (const float*)d_in[3];
    float* out = (float*)d_out;

    unsigned short* hbuf = (unsigned short*)d_ws;           // 3,200,000 bf16 (6.4 MB)
    unsigned* cv    = (unsigned*)(hbuf + N_NODES * OUT_CH); // 196*16384 u32 (12.85 MB)
    float* s        = (float*)(cv + NBIN * 256 * MAXDEG);   // 50,000
    float* t        = s + N_NODES;                          // 50,000
    int* bin_count  = (int*)(t + N_NODES);                  // 196
    float* Zsum     = (float*)(bin_count + NBIN);           // 1
    unsigned* binned= (unsigned*)(Zsum + 1);                // 196*4608 u32 (3.6 MB)
    int* count      = (int*)(binned + NBIN * BINCAP);       // 50,000 (written coalesced)

    const int4* ei4 = (const int4*)eidx;              // destinations
    const int4* ej4 = (const int4*)(eidx + N_EDGES);  // sources

    hipMemsetAsync(bin_count, 0, (NBIN + 1) * sizeof(int), stream);  // bin_count + Zsum
    gemm_bin   <<<NBLK_G + NBLK_A, 256, 0, stream>>>(x, W, attn, ei4, ej4,
                                                     hbuf, s, t, bin_count, binned);
    weight_pass<<<NBIN, 1024, 0, stream>>>(binned, bin_count, s, t, cv, count, Zsum);
    gather_out <<<N_NODES / 4, 256, 0, stream>>>(count, cv, Zsum, hbuf, out);
}